// Round 14
// baseline (142.834 us; speedup 1.0000x reference)
//
#include <hip/hip_runtime.h>
#include <cstdint>

#define NN    1024
#define MM    32
#define NEDGE 32240
#define MROWS 64480   // 2*NEDGE
#define PX    168     // X tile pitch (ushorts); 336B stride -> 2-way LDS conflicts only
#define PST   392     // H pitch: 256 (H1n) + 128 (H1e) + 8 pad
#define PLB   104     // LB pitch (96+8), overlays H in phase 3
#define PHE   72      // HE pitch (64+8), dedicated buffer

typedef unsigned short ushort_t;

typedef __bf16 bf16x8 __attribute__((ext_vector_type(8)));
typedef float  floatx4 __attribute__((ext_vector_type(4)));

__device__ __forceinline__ float b2f(ushort_t u) {
    union { unsigned int i; float f; } v; v.i = ((unsigned int)u) << 16; return v.f;
}
// RNE bf16 via hardware cvt (identical rounding to the old bit-trick, 1 VALU op vs 5)
__device__ __forceinline__ ushort_t f2b(float f) {
    return __builtin_bit_cast(ushort_t, (__bf16)f);
}
// K(i): number of edges before node i
__device__ __forceinline__ int edge_base(int i) {
    return (i <= MM) ? ((i * (i - 1)) >> 1) : (496 + (i - MM) * MM);
}

// ---------------- pack: weight transpose + nodes bf16 (edges read fp32 directly by k_main) ----------------
__global__ __launch_bounds__(256) void k_pack(
        const float* an1, const float* an2, const float* ae1, const float* ae2,
        const float* le1, const float* le2, const float* ln1, const float* ln2,
        const float* nodes,
        ushort_t* pan1, ushort_t* pan2, ushort_t* pae1, ushort_t* pae2,
        ushort_t* ple1, ushort_t* ple2, ushort_t* pln1, ushort_t* pln2,
        ushort_t* nodesb) {
    __shared__ float tile[32][33];
    const int bid = blockIdx.x;
    const int tid = threadIdx.x;
    if (bid < 152) {
        const float* s; ushort_t* d; int K, N, t;
        if (bid < 40)       { s = an1; d = pan1; K = 160; N = 256; t = bid;       }
        else if (bid < 72)  { s = an2; d = pan2; K = 256; N = 128; t = bid - 40;  }
        else if (bid < 84)  { s = ae1; d = pae1; K = 96;  N = 128; t = bid - 72;  }
        else if (bid < 92)  { s = ae2; d = pae2; K = 128; N = 64;  t = bid - 84;  }
        else if (bid < 101) { s = le1; d = ple1; K = 96;  N = 96;  t = bid - 92;  }
        else if (bid < 104) { s = le2; d = ple2; K = 96;  N = 32;  t = bid - 101; }
        else if (bid < 140) { s = ln1; d = pln1; K = 192; N = 192; t = bid - 104; }
        else                { s = ln2; d = pln2; K = 192; N = 64;  t = bid - 140; }
        int ntn = N >> 5;
        int tk = t / ntn, tn = t - tk * ntn;
        int k0 = tk * 32, n0 = tn * 32;
        int tx = tid & 31, ty = tid >> 5;
#pragma unroll
        for (int m = 0; m < 4; ++m)
            tile[ty + m * 8][tx] = s[(size_t)(k0 + ty + m * 8) * N + n0 + tx];
        __syncthreads();
#pragma unroll
        for (int m = 0; m < 4; ++m)
            d[(size_t)(n0 + ty + m * 8) * K + k0 + tx] = f2b(tile[tx][ty + m * 8]);
    } else {
        int i4 = (bid - 152) * 256 + tid;
        float4 v = ((const float4*)nodes)[i4];
        uint2 o;
        o.x = (unsigned)f2b(v.x) | ((unsigned)f2b(v.y) << 16);
        o.y = (unsigned)f2b(v.z) | ((unsigned)f2b(v.w) << 16);
        ((uint2*)nodesb)[i4] = o;
    }
}

// ---------------- main: batch-paired per-node block, P2 REBALANCED (round-13 change) ----------------
// One block per node i (1024 blocks), 512 thr = 8 waves, both batches b=0,1. 4 barriers.
// P1: an1 160->256 (wave w -> col-tiles {w,w+8}) + ae1 96->128 (tile w), shared A frags, bb=0,1.
// P2 (rebalanced): an2's 8 col-tiles -> ONE PER WAVE (32 MFMA each, 8 frags) + pn write;
//     waves 0-3 additionally ae2 tile w (16 MFMA, 4 frags) -> HE + same-wave prefix-mean
//     -> pre into X[bb][16w..16w+15]. Longest path 64->48 MFMA, 16->12 frags (vs round 11).
// P3: waves 0-5 le1 96->96 (tile w) -> LB overlays H. P4: waves 0-3 le2 96->32 -> out_edges (rows<t).
// P2/P3/P4 weight loads hoisted BEFORE their preceding barrier (latency absorbed by barrier wait).
// launch_bounds min-waves=4 (NOT 8: 8 forced VGPR=32 -> scratch spill, round-5 regression).
__global__ __launch_bounds__(512, 4) void k_main(
        const ushort_t* __restrict__ nodesb, const float* __restrict__ edges,
        const ushort_t* __restrict__ pan1, const float* __restrict__ ban1,
        const ushort_t* __restrict__ pan2, const float* __restrict__ ban2,
        const ushort_t* __restrict__ pae1, const float* __restrict__ bae1,
        const ushort_t* __restrict__ pae2, const float* __restrict__ bae2,
        const ushort_t* __restrict__ ple1, const float* __restrict__ ble1,
        const ushort_t* __restrict__ ple2, const float* __restrict__ ble2,
        ushort_t* __restrict__ pn, float* __restrict__ out_edges) {
    __shared__ alignas(16) ushort_t X[2][32 * PX];    // 21504 B
    __shared__ alignas(16) ushort_t H[2][32 * PST];   // 50176 B
    __shared__ alignas(16) ushort_t HE[2][32 * PHE];  // 9216 B; total 80896 B -> 2 blocks/CU
    const int tid = threadIdx.x;
    const int w = tid >> 6, l = tid & 63, lrow = l & 15, lq = l >> 4;
    const int i = blockIdx.x;
    const int t = min(i, MM);
    floatx4 zero = {0.f, 0.f, 0.f, 0.f};

    if (i == 0) {                     // pn rows 0 and 1024 = zeros; no edges (uniform, pre-barrier)
        if (tid < 64)       ((unsigned*)pn)[tid] = 0u;
        else if (tid < 128) ((unsigned*)(pn + (size_t)1024 * 128))[tid - 64] = 0u;
        return;
    }
    const int j0 = i - t;
    const int eb0 = edge_base(i);

    // phase-1 weight fragments (issued before gather for latency overlap)
    bf16x8 B0[5], B1[5], B2[3];
#pragma unroll
    for (int kt = 0; kt < 5; ++kt) {
        B0[kt] = *(const bf16x8*)(pan1 + (size_t)(16 * w + lrow) * 160 + kt * 32 + lq * 8);
        B1[kt] = *(const bf16x8*)(pan1 + (size_t)(16 * (w + 8) + lrow) * 160 + kt * 32 + lq * 8);
    }
#pragma unroll
    for (int kt = 0; kt < 3; ++kt)
        B2[kt] = *(const bf16x8*)(pae1 + (size_t)(16 * w + lrow) * 96 + kt * 32 + lq * 8);
    const float c0 = ban1[16 * w + lrow];
    const float c1 = ban1[16 * (w + 8) + lrow];
    const float c2 = bae1[16 * w + lrow];

    // gather both batches: row rr -> [nj(32u) | eb(16u, cvt fp32) | ni(32u)]
#pragma unroll
    for (int bb = 0; bb < 2; ++bb) {
        const int base = bb * NEDGE + eb0;
#pragma unroll
        for (int k = 0; k < 4; ++k) {
            int rr = w * 4 + k;
            unsigned* xr = (unsigned*)(X[bb] + rr * PX);
            const unsigned* nj = (const unsigned*)(nodesb + (size_t)(bb * NN + j0 + rr) * 64);
            const unsigned* ni = (const unsigned*)(nodesb + (size_t)(bb * NN + i) * 64);
            if (l < 32) { xr[l] = nj[l]; xr[48 + l] = ni[l]; }
            else if (l < 48) {
                float2 e = *(const float2*)(edges + (size_t)(base + rr) * 32 + 2 * (l - 32));
                xr[l] = (unsigned)f2b(e.x) | ((unsigned)f2b(e.y) << 16);
            }
        }
    }
    __syncthreads();   // A: both X ready

    // phase 1: an1 (tiles {w, w+8}) + ae1 (tile w), both batches, A fragments shared per bb
#pragma unroll
    for (int bb = 0; bb < 2; ++bb)
#pragma unroll
        for (int s = 0; s < 2; ++s) {
            bf16x8 A[5];
#pragma unroll
            for (int kt = 0; kt < 5; ++kt)
                A[kt] = *(const bf16x8*)&X[bb][(s * 16 + lrow) * PX + kt * 32 + lq * 8];
            floatx4 a0 = zero, a1 = zero, a2 = zero;
#pragma unroll
            for (int kt = 0; kt < 5; ++kt) {
                a0 = __builtin_amdgcn_mfma_f32_16x16x32_bf16(A[kt], B0[kt], a0, 0, 0, 0);
                a1 = __builtin_amdgcn_mfma_f32_16x16x32_bf16(A[kt], B1[kt], a1, 0, 0, 0);
            }
#pragma unroll
            for (int kt = 0; kt < 3; ++kt)
                a2 = __builtin_amdgcn_mfma_f32_16x16x32_bf16(A[kt], B2[kt], a2, 0, 0, 0);
#pragma unroll
            for (int r_ = 0; r_ < 4; ++r_) {
                int row = (s * 16 + lq * 4 + r_) * PST;
                H[bb][row + 16 * w + lrow]       = f2b(fmaxf(a0[r_] + c0, 0.f));
                H[bb][row + 128 + 16 * w + lrow] = f2b(fmaxf(a1[r_] + c1, 0.f));
                H[bb][row + 256 + 16 * w + lrow] = f2b(fmaxf(a2[r_] + c2, 0.f));
            }
        }

    // hoist phase-2 weights: ALL waves an2 tile w; waves 0-3 also ae2 tile w
    bf16x8 D[8], E[4];
#pragma unroll
    for (int kt = 0; kt < 8; ++kt)
        D[kt] = *(const bf16x8*)(pan2 + (size_t)(16 * w + lrow) * 256 + kt * 32 + lq * 8);
    const float d0 = ban2[16 * w + lrow];
    float d2 = 0.f;
    if (w < 4) {
#pragma unroll
        for (int kt = 0; kt < 4; ++kt)
            E[kt] = *(const bf16x8*)(pae2 + (size_t)(16 * w + lrow) * 128 + kt * 32 + lq * 8);
        d2 = bae2[16 * w + lrow];
    }
    __syncthreads();   // B: both H ready; X reads drained

    // phase 2a: an2 col-tile w on EVERY wave + in-reg masked window mean -> pn
#pragma unroll
    for (int bb = 0; bb < 2; ++bb) {
        float P0 = 0.f;
#pragma unroll
        for (int s = 0; s < 2; ++s) {
            floatx4 a0 = zero;
#pragma unroll
            for (int kt = 0; kt < 8; ++kt) {
                bf16x8 a = *(const bf16x8*)&H[bb][(s * 16 + lrow) * PST + kt * 32 + lq * 8];
                a0 = __builtin_amdgcn_mfma_f32_16x16x32_bf16(a, D[kt], a0, 0, 0, 0);
            }
#pragma unroll
            for (int r_ = 0; r_ < 4; ++r_) {
                int row = s * 16 + lq * 4 + r_;
                float v0 = b2f(f2b(fmaxf(a0[r_] + d0, 0.f)));   // bf16-rounded (k_mid-identical)
                if (row < t) P0 += v0;
            }
        }
        P0 += __shfl_xor(P0, 16); P0 += __shfl_xor(P0, 32);
        if (l < 16)
            pn[(size_t)(bb * 1024 + i) * 128 + 16 * w + lrow] = f2b(P0 * (1.0f / (float)t));
    }
    // phase 2b: waves 0-3 ae2 tile w -> HE + same-wave prefix-mean -> pre into X[bb][16w..]
    if (w < 4) {
#pragma unroll
        for (int bb = 0; bb < 2; ++bb)
#pragma unroll
            for (int s = 0; s < 2; ++s) {
                floatx4 a2 = zero;
#pragma unroll
                for (int kt = 0; kt < 4; ++kt) {
                    bf16x8 a = *(const bf16x8*)&H[bb][(s * 16 + lrow) * PST + 256 + kt * 32 + lq * 8];
                    a2 = __builtin_amdgcn_mfma_f32_16x16x32_bf16(a, E[kt], a2, 0, 0, 0);
                }
#pragma unroll
                for (int r_ = 0; r_ < 4; ++r_)
                    HE[bb][(s * 16 + lq * 4 + r_) * PHE + 16 * w + lrow] = f2b(fmaxf(a2[r_] + d2, 0.f));
            }
        // unrolled prefix-mean over this wave's own 16 HE cols (same-wave LDS RAW; no barrier)
        if (l < 16) {
#pragma unroll
            for (int bb = 0; bb < 2; ++bb) {
                float h[32];
#pragma unroll
                for (int p = 0; p < 32; ++p)
                    h[p] = b2f(HE[bb][p * PHE + 16 * w + l]);
                float run = 0.f;
#pragma unroll
                for (int p = 0; p < 32; ++p) {
                    if (p < t)
                        X[bb][p * PX + 16 * w + l] = f2b((p == 0) ? 0.f : run * (1.0f / (float)p));
                    run += h[p];
                }
            }
        }
    }
    // hoist phase-3 weights
    bf16x8 F0[3]; float v0 = 0.f;
    if (w < 6) {
#pragma unroll
        for (int kt = 0; kt < 3; ++kt)
            F0[kt] = *(const bf16x8*)(ple1 + (size_t)(16 * w + lrow) * 96 + kt * 32 + lq * 8);
        v0 = ble1[16 * w + lrow];
    }
    __syncthreads();   // C: pre ready; H reads drained -> LB may overlay H

    // phase 3: le1 96->96, waves 0..5 -> col-tile w; input X[bb][0..95] = [pre|eb], out LB (=H, PLB)
    if (w < 6) {
#pragma unroll
        for (int bb = 0; bb < 2; ++bb)
#pragma unroll
            for (int s = 0; s < 2; ++s) {
                bf16x8 A[3];
#pragma unroll
                for (int kt = 0; kt < 3; ++kt)
                    A[kt] = *(const bf16x8*)&X[bb][(s * 16 + lrow) * PX + kt * 32 + lq * 8];
                floatx4 a0 = zero;
#pragma unroll
                for (int kt = 0; kt < 3; ++kt)
                    a0 = __builtin_amdgcn_mfma_f32_16x16x32_bf16(A[kt], F0[kt], a0, 0, 0, 0);
#pragma unroll
                for (int r_ = 0; r_ < 4; ++r_)
                    H[bb][(s * 16 + lq * 4 + r_) * PLB + 16 * w + lrow] = f2b(fmaxf(a0[r_] + v0, 0.f));
            }
    }
    // hoist phase-4 weights
    const int ct = w & 1, s2 = w >> 1, c0o = 16 * ct;
    bf16x8 F2[3]; float v2 = 0.f;
    if (w < 4) {
#pragma unroll
        for (int kt = 0; kt < 3; ++kt)
            F2[kt] = *(const bf16x8*)(ple2 + (size_t)(c0o + lrow) * 96 + kt * 32 + lq * 8);
        v2 = ble2[c0o + lrow];
    }
    __syncthreads();   // D: LB ready

    // phase 4: le2 96->32, waves 0..3: col-tile (w&1), row-half (w>>1); stores guarded rows < t
    if (w < 4) {
#pragma unroll
        for (int bb = 0; bb < 2; ++bb) {
            floatx4 a2 = zero;
#pragma unroll
            for (int kt = 0; kt < 3; ++kt) {
                bf16x8 a = *(const bf16x8*)&H[bb][(s2 * 16 + lrow) * PLB + kt * 32 + lq * 8];
                a2 = __builtin_amdgcn_mfma_f32_16x16x32_bf16(a, F2[kt], a2, 0, 0, 0);
            }
            const int base = bb * NEDGE + eb0;
#pragma unroll
            for (int r_ = 0; r_ < 4; ++r_) {
                int grow = s2 * 16 + lq * 4 + r_;
                if (grow < t)
                    out_edges[(size_t)(base + grow) * 32 + c0o + lrow] = fmaxf(a2[r_] + v2, 0.f);
            }
        }
    }
}

// ---------------- final: node MLP ([pn|nodesb] 192->192->64) ----------------
__global__ __launch_bounds__(192) void k_final(
        const ushort_t* __restrict__ pn, const ushort_t* __restrict__ nodesb,
        const ushort_t* __restrict__ pln1, const float* __restrict__ bln1,
        const ushort_t* __restrict__ pln2, const float* __restrict__ bln2,
        float* __restrict__ out_nodes) {
    __shared__ alignas(16) ushort_t LA[32 * 200];
    __shared__ alignas(16) ushort_t LB[32 * 200];
    const int tid = threadIdx.x;
    const int w = tid >> 6, l = tid & 63, lrow = l & 15, lq = l >> 4;
    floatx4 zero = {0.f, 0.f, 0.f, 0.f};

    int tile = blockIdx.x;
    for (int u = tid; u < 768; u += 192) {        // 32 rows x 24 uint4 chunks
        int row = u / 24, c = u - row * 24;
        int r = tile * 32 + row;
        const uint4* src = (c < 16) ? ((const uint4*)(pn + (size_t)r * 128) + c)
                                    : ((const uint4*)(nodesb + (size_t)r * 64) + (c - 16));
        *(uint4*)&LA[row * 200 + c * 8] = *src;
    }
    bf16x8 f1[6][4]; float v1[4];
#pragma unroll
    for (int kt = 0; kt < 6; ++kt)
#pragma unroll
        for (int nt = 0; nt < 4; ++nt)
            f1[kt][nt] = *(const bf16x8*)(pln1 + (size_t)(w * 64 + nt * 16 + lrow) * 192 + kt * 32 + lq * 8);
#pragma unroll
    for (int nt = 0; nt < 4; ++nt) v1[nt] = bln1[w * 64 + nt * 16 + lrow];
    __syncthreads();

    floatx4 acc[2][4];
#pragma unroll
    for (int s = 0; s < 2; ++s)
#pragma unroll
        for (int nt = 0; nt < 4; ++nt) acc[s][nt] = zero;
#pragma unroll
    for (int s = 0; s < 2; ++s)
#pragma unroll
        for (int kt = 0; kt < 6; ++kt) {
            bf16x8 a = *(const bf16x8*)&LA[(s * 16 + lrow) * 200 + kt * 32 + lq * 8];
#pragma unroll
            for (int nt = 0; nt < 4; ++nt)
                acc[s][nt] = __builtin_amdgcn_mfma_f32_16x16x32_bf16(a, f1[kt][nt], acc[s][nt], 0, 0, 0);
        }
#pragma unroll
    for (int s = 0; s < 2; ++s)
#pragma unroll
        for (int nt = 0; nt < 4; ++nt) {
            int col = w * 64 + nt * 16 + lrow;
#pragma unroll
            for (int r_ = 0; r_ < 4; ++r_)
                LB[(s * 16 + lq * 4 + r_) * 200 + col] = f2b(fmaxf(acc[s][nt][r_] + v1[nt], 0.f));
        }
    bf16x8 f2[6][2]; float v2[2] = {0.f, 0.f};
    if (w < 2) {
#pragma unroll
        for (int kt = 0; kt < 6; ++kt)
#pragma unroll
            for (int nt = 0; nt < 2; ++nt)
                f2[kt][nt] = *(const bf16x8*)(pln2 + (size_t)(w * 32 + nt * 16 + lrow) * 192 + kt * 32 + lq * 8);
#pragma unroll
        for (int nt = 0; nt < 2; ++nt) v2[nt] = bln2[w * 32 + nt * 16 + lrow];
    }
    __syncthreads();
    if (w < 2) {
        floatx4 a2[2][2];
#pragma unroll
        for (int s = 0; s < 2; ++s) { a2[s][0] = zero; a2[s][1] = zero; }
#pragma unroll
        for (int s = 0; s < 2; ++s)
#pragma unroll
            for (int kt = 0; kt < 6; ++kt) {
                bf16x8 a = *(const bf16x8*)&LB[(s * 16 + lrow) * 200 + kt * 32 + lq * 8];
#pragma unroll
                for (int nt = 0; nt < 2; ++nt)
                    a2[s][nt] = __builtin_amdgcn_mfma_f32_16x16x32_bf16(a, f2[kt][nt], a2[s][nt], 0, 0, 0);
            }
#pragma unroll
        for (int s = 0; s < 2; ++s)
#pragma unroll
            for (int nt = 0; nt < 2; ++nt) {
                int col = w * 32 + nt * 16 + lrow;
#pragma unroll
                for (int r_ = 0; r_ < 4; ++r_)
                    out_nodes[(size_t)(tile * 32 + s * 16 + lq * 4 + r_) * 64 + col] =
                        fmaxf(a2[s][nt][r_] + v2[nt], 0.f);
            }
    }
}

extern "C" void kernel_launch(void* const* d_in, const int* in_sizes, int n_in,
                              void* d_out, int out_size, void* d_ws, size_t ws_size,
                              hipStream_t stream) {
    const float* nodes = (const float*)d_in[0];
    const float* edges = (const float*)d_in[1];
    const float* Wan1 = (const float*)d_in[2];  const float* ban1 = (const float*)d_in[3];
    const float* Wan2 = (const float*)d_in[4];  const float* ban2 = (const float*)d_in[5];
    const float* Wln1 = (const float*)d_in[6];  const float* bln1 = (const float*)d_in[7];
    const float* Wln2 = (const float*)d_in[8];  const float* bln2 = (const float*)d_in[9];
    const float* Wae1 = (const float*)d_in[10]; const float* bae1 = (const float*)d_in[11];
    const float* Wae2 = (const float*)d_in[12]; const float* bae2 = (const float*)d_in[13];
    const float* Wle1 = (const float*)d_in[14]; const float* ble1 = (const float*)d_in[15];
    const float* Wle2 = (const float*)d_in[16]; const float* ble2 = (const float*)d_in[17];

    char* ws = (char*)d_ws;
    size_t o = 0;
    auto alloc = [&](size_t bytes) -> void* {
        void* r = ws + o;
        o += (bytes + 255) & ~(size_t)255;
        return r;
    };
    ushort_t* pn     = (ushort_t*)alloc((size_t)2048 * 128 * 2);
    ushort_t* nodesb = (ushort_t*)alloc((size_t)2 * NN * 64 * 2);
    ushort_t* pan1 = (ushort_t*)alloc(160 * 256 * 2);
    ushort_t* pan2 = (ushort_t*)alloc(256 * 128 * 2);
    ushort_t* pae1 = (ushort_t*)alloc(96 * 128 * 2);
    ushort_t* pae2 = (ushort_t*)alloc(128 * 64 * 2);
    ushort_t* ple1 = (ushort_t*)alloc(96 * 96 * 2);
    ushort_t* ple2 = (ushort_t*)alloc(96 * 32 * 2);
    ushort_t* pln1 = (ushort_t*)alloc(192 * 192 * 2);
    ushort_t* pln2 = (ushort_t*)alloc(192 * 64 * 2);

    float* out_nodes = (float*)d_out;
    float* out_edges = (float*)d_out + 2 * NN * 64;

    k_pack<<<280, 256, 0, stream>>>(Wan1, Wan2, Wae1, Wae2, Wle1, Wle2, Wln1, Wln2,
                                    nodes,
                                    pan1, pan2, pae1, pae2, ple1, ple2, pln1, pln2,
                                    nodesb);
    k_main<<<1024, 512, 0, stream>>>(nodesb, edges,
                                     pan1, ban1, pan2, ban2,
                                     pae1, bae1, pae2, bae2,
                                     ple1, ble1, ple2, ble2,
                                     pn, out_edges);
    k_final<<<64, 192, 0, stream>>>(pn, nodesb, pln1, bln1, pln2, bln2, out_nodes);

    (void)in_sizes; (void)n_in; (void)out_size; (void)ws_size;
}

// Round 15
// 140.567 us; speedup vs baseline: 1.0161x; 1.0161x over previous
//
#include <hip/hip_runtime.h>
#include <cstdint>

#define NN    1024
#define MM    32
#define NEDGE 32240
#define MROWS 64480   // 2*NEDGE
#define PX    168     // X tile pitch (ushorts); 336B stride -> 2-way LDS conflicts only
#define PST   392     // H pitch: 256 (H1n) + 128 (H1e) + 8 pad
#define PLB   104     // LB pitch (96+8), overlays H in phase 3
#define PHE   72      // HE pitch (64+8), dedicated buffer

typedef unsigned short ushort_t;

typedef __bf16 bf16x8 __attribute__((ext_vector_type(8)));
typedef float  floatx4 __attribute__((ext_vector_type(4)));

__device__ __forceinline__ float b2f(ushort_t u) {
    union { unsigned int i; float f; } v; v.i = ((unsigned int)u) << 16; return v.f;
}
// RNE bf16 via hardware cvt (identical rounding to the old bit-trick, 1 VALU op vs 5)
__device__ __forceinline__ ushort_t f2b(float f) {
    return __builtin_bit_cast(ushort_t, (__bf16)f);
}
// K(i): number of edges before node i
__device__ __forceinline__ int edge_base(int i) {
    return (i <= MM) ? ((i * (i - 1)) >> 1) : (496 + (i - MM) * MM);
}

// ---------------- pack: weight transpose + nodes bf16 (edges read fp32 directly by k_main) ----------------
__global__ __launch_bounds__(256) void k_pack(
        const float* an1, const float* an2, const float* ae1, const float* ae2,
        const float* le1, const float* le2, const float* ln1, const float* ln2,
        const float* nodes,
        ushort_t* pan1, ushort_t* pan2, ushort_t* pae1, ushort_t* pae2,
        ushort_t* ple1, ushort_t* ple2, ushort_t* pln1, ushort_t* pln2,
        ushort_t* nodesb) {
    __shared__ float tile[32][33];
    const int bid = blockIdx.x;
    const int tid = threadIdx.x;
    if (bid < 152) {
        const float* s; ushort_t* d; int K, N, t;
        if (bid < 40)       { s = an1; d = pan1; K = 160; N = 256; t = bid;       }
        else if (bid < 72)  { s = an2; d = pan2; K = 256; N = 128; t = bid - 40;  }
        else if (bid < 84)  { s = ae1; d = pae1; K = 96;  N = 128; t = bid - 72;  }
        else if (bid < 92)  { s = ae2; d = pae2; K = 128; N = 64;  t = bid - 84;  }
        else if (bid < 101) { s = le1; d = ple1; K = 96;  N = 96;  t = bid - 92;  }
        else if (bid < 104) { s = le2; d = ple2; K = 96;  N = 32;  t = bid - 101; }
        else if (bid < 140) { s = ln1; d = pln1; K = 192; N = 192; t = bid - 104; }
        else                { s = ln2; d = pln2; K = 192; N = 64;  t = bid - 140; }
        int ntn = N >> 5;
        int tk = t / ntn, tn = t - tk * ntn;
        int k0 = tk * 32, n0 = tn * 32;
        int tx = tid & 31, ty = tid >> 5;
#pragma unroll
        for (int m = 0; m < 4; ++m)
            tile[ty + m * 8][tx] = s[(size_t)(k0 + ty + m * 8) * N + n0 + tx];
        __syncthreads();
#pragma unroll
        for (int m = 0; m < 4; ++m)
            d[(size_t)(n0 + ty + m * 8) * K + k0 + tx] = f2b(tile[tx][ty + m * 8]);
    } else {
        int i4 = (bid - 152) * 256 + tid;
        float4 v = ((const float4*)nodes)[i4];
        uint2 o;
        o.x = (unsigned)f2b(v.x) | ((unsigned)f2b(v.y) << 16);
        o.y = (unsigned)f2b(v.z) | ((unsigned)f2b(v.w) << 16);
        ((uint2*)nodesb)[i4] = o;
    }
}

// ---------------- main: batch-paired per-node block (both b=0,1 of node i), 4 barriers ----------------
// CHAMPION (round-11, 142.2 us total): one block per node i (1024 blocks), 512 thr = 8 waves.
// Both batches share ALL weight fragments; each phase runs bb=0,1 -> 2 independent MFMA chains.
// P1: an1 160->256 (wave w -> col-tiles {w,w+8}) + ae1 96->128 (tile w), shared A frags, bb=0,1.
// P2: waves 0-3 an2 256->128 (tiles {w,w+4}) + in-reg masked window mean -> pn (shfl reduce);
//     waves 4-7 ae2 128->64 (tile w-4) -> HE + unrolled prefix-mean -> pre into X[bb][0..63].
// P3: waves 0-5 le1 96->96 (tile w) -> LB overlays H. P4: waves 0-3 le2 96->32 -> out_edges (rows<t).
// P2/P3/P4 weight loads hoisted BEFORE their preceding barrier (latency absorbed by barrier wait).
// launch_bounds min-waves=4 (NOT 8: 8 forced VGPR=32 -> scratch spill, round-5 regression).
__global__ __launch_bounds__(512, 4) void k_main(
        const ushort_t* __restrict__ nodesb, const float* __restrict__ edges,
        const ushort_t* __restrict__ pan1, const float* __restrict__ ban1,
        const ushort_t* __restrict__ pan2, const float* __restrict__ ban2,
        const ushort_t* __restrict__ pae1, const float* __restrict__ bae1,
        const ushort_t* __restrict__ pae2, const float* __restrict__ bae2,
        const ushort_t* __restrict__ ple1, const float* __restrict__ ble1,
        const ushort_t* __restrict__ ple2, const float* __restrict__ ble2,
        ushort_t* __restrict__ pn, float* __restrict__ out_edges) {
    __shared__ alignas(16) ushort_t X[2][32 * PX];    // 21504 B
    __shared__ alignas(16) ushort_t H[2][32 * PST];   // 50176 B
    __shared__ alignas(16) ushort_t HE[2][32 * PHE];  // 9216 B; total 80896 B -> 2 blocks/CU
    const int tid = threadIdx.x;
    const int w = tid >> 6, l = tid & 63, lrow = l & 15, lq = l >> 4;
    const int i = blockIdx.x;
    const int t = min(i, MM);
    floatx4 zero = {0.f, 0.f, 0.f, 0.f};

    if (i == 0) {                     // pn rows 0 and 1024 = zeros; no edges (uniform, pre-barrier)
        if (tid < 64)       ((unsigned*)pn)[tid] = 0u;
        else if (tid < 128) ((unsigned*)(pn + (size_t)1024 * 128))[tid - 64] = 0u;
        return;
    }
    const int j0 = i - t;
    const int eb0 = edge_base(i);

    // phase-1 weight fragments (issued before gather for latency overlap)
    bf16x8 B0[5], B1[5], B2[3];
#pragma unroll
    for (int kt = 0; kt < 5; ++kt) {
        B0[kt] = *(const bf16x8*)(pan1 + (size_t)(16 * w + lrow) * 160 + kt * 32 + lq * 8);
        B1[kt] = *(const bf16x8*)(pan1 + (size_t)(16 * (w + 8) + lrow) * 160 + kt * 32 + lq * 8);
    }
#pragma unroll
    for (int kt = 0; kt < 3; ++kt)
        B2[kt] = *(const bf16x8*)(pae1 + (size_t)(16 * w + lrow) * 96 + kt * 32 + lq * 8);
    const float c0 = ban1[16 * w + lrow];
    const float c1 = ban1[16 * (w + 8) + lrow];
    const float c2 = bae1[16 * w + lrow];

    // gather both batches: row rr -> [nj(32u) | eb(16u, cvt fp32) | ni(32u)]
#pragma unroll
    for (int bb = 0; bb < 2; ++bb) {
        const int base = bb * NEDGE + eb0;
#pragma unroll
        for (int k = 0; k < 4; ++k) {
            int rr = w * 4 + k;
            unsigned* xr = (unsigned*)(X[bb] + rr * PX);
            const unsigned* nj = (const unsigned*)(nodesb + (size_t)(bb * NN + j0 + rr) * 64);
            const unsigned* ni = (const unsigned*)(nodesb + (size_t)(bb * NN + i) * 64);
            if (l < 32) { xr[l] = nj[l]; xr[48 + l] = ni[l]; }
            else if (l < 48) {
                float2 e = *(const float2*)(edges + (size_t)(base + rr) * 32 + 2 * (l - 32));
                xr[l] = (unsigned)f2b(e.x) | ((unsigned)f2b(e.y) << 16);
            }
        }
    }
    __syncthreads();   // A: both X ready

    // phase 1: an1 (tiles {w, w+8}) + ae1 (tile w), both batches, A fragments shared per bb
#pragma unroll
    for (int bb = 0; bb < 2; ++bb)
#pragma unroll
        for (int s = 0; s < 2; ++s) {
            bf16x8 A[5];
#pragma unroll
            for (int kt = 0; kt < 5; ++kt)
                A[kt] = *(const bf16x8*)&X[bb][(s * 16 + lrow) * PX + kt * 32 + lq * 8];
            floatx4 a0 = zero, a1 = zero, a2 = zero;
#pragma unroll
            for (int kt = 0; kt < 5; ++kt) {
                a0 = __builtin_amdgcn_mfma_f32_16x16x32_bf16(A[kt], B0[kt], a0, 0, 0, 0);
                a1 = __builtin_amdgcn_mfma_f32_16x16x32_bf16(A[kt], B1[kt], a1, 0, 0, 0);
            }
#pragma unroll
            for (int kt = 0; kt < 3; ++kt)
                a2 = __builtin_amdgcn_mfma_f32_16x16x32_bf16(A[kt], B2[kt], a2, 0, 0, 0);
#pragma unroll
            for (int r_ = 0; r_ < 4; ++r_) {
                int row = (s * 16 + lq * 4 + r_) * PST;
                H[bb][row + 16 * w + lrow]       = f2b(fmaxf(a0[r_] + c0, 0.f));
                H[bb][row + 128 + 16 * w + lrow] = f2b(fmaxf(a1[r_] + c1, 0.f));
                H[bb][row + 256 + 16 * w + lrow] = f2b(fmaxf(a2[r_] + c2, 0.f));
            }
        }

    // hoist phase-2 weights (load latency absorbed by barrier-B wait)
    bf16x8 D0[8], D1[8], E[4];
    float d0 = 0.f, d1 = 0.f, d2 = 0.f;
    if (w < 4) {
#pragma unroll
        for (int kt = 0; kt < 8; ++kt) {
            D0[kt] = *(const bf16x8*)(pan2 + (size_t)(16 * w + lrow) * 256 + kt * 32 + lq * 8);
            D1[kt] = *(const bf16x8*)(pan2 + (size_t)(16 * (w + 4) + lrow) * 256 + kt * 32 + lq * 8);
        }
        d0 = ban2[16 * w + lrow];
        d1 = ban2[16 * (w + 4) + lrow];
    } else {
        int u = w - 4;
#pragma unroll
        for (int kt = 0; kt < 4; ++kt)
            E[kt] = *(const bf16x8*)(pae2 + (size_t)(16 * u + lrow) * 128 + kt * 32 + lq * 8);
        d2 = bae2[16 * u + lrow];
    }
    __syncthreads();   // B: both H ready; X reads drained

    // phase 2: split waves, both batches
    if (w < 4) {
#pragma unroll
        for (int bb = 0; bb < 2; ++bb) {
            float P0 = 0.f, P1 = 0.f;
#pragma unroll
            for (int s = 0; s < 2; ++s) {
                floatx4 a0 = zero, a1 = zero;
#pragma unroll
                for (int kt = 0; kt < 8; ++kt) {
                    bf16x8 a = *(const bf16x8*)&H[bb][(s * 16 + lrow) * PST + kt * 32 + lq * 8];
                    a0 = __builtin_amdgcn_mfma_f32_16x16x32_bf16(a, D0[kt], a0, 0, 0, 0);
                    a1 = __builtin_amdgcn_mfma_f32_16x16x32_bf16(a, D1[kt], a1, 0, 0, 0);
                }
#pragma unroll
                for (int r_ = 0; r_ < 4; ++r_) {
                    int row = s * 16 + lq * 4 + r_;
                    float v0 = b2f(f2b(fmaxf(a0[r_] + d0, 0.f)));   // bf16-rounded
                    float v1 = b2f(f2b(fmaxf(a1[r_] + d1, 0.f)));
                    if (row < t) { P0 += v0; P1 += v1; }
                }
            }
            P0 += __shfl_xor(P0, 16); P0 += __shfl_xor(P0, 32);
            P1 += __shfl_xor(P1, 16); P1 += __shfl_xor(P1, 32);
            if (l < 16) {
                float inv = 1.0f / (float)t;
                pn[(size_t)(bb * 1024 + i) * 128 + 16 * w + lrow]       = f2b(P0 * inv);
                pn[(size_t)(bb * 1024 + i) * 128 + 16 * (w + 4) + lrow] = f2b(P1 * inv);
            }
        }
    } else {
        int u = w - 4;
#pragma unroll
        for (int bb = 0; bb < 2; ++bb)
#pragma unroll
            for (int s = 0; s < 2; ++s) {
                floatx4 a2 = zero;
#pragma unroll
                for (int kt = 0; kt < 4; ++kt) {
                    bf16x8 a = *(const bf16x8*)&H[bb][(s * 16 + lrow) * PST + 256 + kt * 32 + lq * 8];
                    a2 = __builtin_amdgcn_mfma_f32_16x16x32_bf16(a, E[kt], a2, 0, 0, 0);
                }
#pragma unroll
                for (int r_ = 0; r_ < 4; ++r_)
                    HE[bb][(s * 16 + lq * 4 + r_) * PHE + 16 * u + lrow] = f2b(fmaxf(a2[r_] + d2, 0.f));
            }
        // unrolled prefix-mean per batch: 32 batched ds_reads (one latency) + register fadd chain
        if (l < 16) {
#pragma unroll
            for (int bb = 0; bb < 2; ++bb) {
                float h[32];
#pragma unroll
                for (int p = 0; p < 32; ++p)
                    h[p] = b2f(HE[bb][p * PHE + 16 * u + l]);
                float run = 0.f;
#pragma unroll
                for (int p = 0; p < 32; ++p) {
                    if (p < t)
                        X[bb][p * PX + 16 * u + l] = f2b((p == 0) ? 0.f : run * (1.0f / (float)p));
                    run += h[p];
                }
            }
        }
    }
    // hoist phase-3 weights
    bf16x8 F0[3]; float v0 = 0.f;
    if (w < 6) {
#pragma unroll
        for (int kt = 0; kt < 3; ++kt)
            F0[kt] = *(const bf16x8*)(ple1 + (size_t)(16 * w + lrow) * 96 + kt * 32 + lq * 8);
        v0 = ble1[16 * w + lrow];
    }
    __syncthreads();   // C: pre ready; H reads drained -> LB may overlay H

    // phase 3: le1 96->96, waves 0..5 -> col-tile w; input X[bb][0..95] = [pre|eb], out LB (=H, PLB)
    if (w < 6) {
#pragma unroll
        for (int bb = 0; bb < 2; ++bb)
#pragma unroll
            for (int s = 0; s < 2; ++s) {
                bf16x8 A[3];
#pragma unroll
                for (int kt = 0; kt < 3; ++kt)
                    A[kt] = *(const bf16x8*)&X[bb][(s * 16 + lrow) * PX + kt * 32 + lq * 8];
                floatx4 a0 = zero;
#pragma unroll
                for (int kt = 0; kt < 3; ++kt)
                    a0 = __builtin_amdgcn_mfma_f32_16x16x32_bf16(A[kt], F0[kt], a0, 0, 0, 0);
#pragma unroll
                for (int r_ = 0; r_ < 4; ++r_)
                    H[bb][(s * 16 + lq * 4 + r_) * PLB + 16 * w + lrow] = f2b(fmaxf(a0[r_] + v0, 0.f));
            }
    }
    // hoist phase-4 weights
    const int ct = w & 1, s2 = w >> 1, c0o = 16 * ct;
    bf16x8 F2[3]; float v2 = 0.f;
    if (w < 4) {
#pragma unroll
        for (int kt = 0; kt < 3; ++kt)
            F2[kt] = *(const bf16x8*)(ple2 + (size_t)(c0o + lrow) * 96 + kt * 32 + lq * 8);
        v2 = ble2[c0o + lrow];
    }
    __syncthreads();   // D: LB ready

    // phase 4: le2 96->32, waves 0..3: col-tile (w&1), row-half (w>>1); stores guarded rows < t
    if (w < 4) {
#pragma unroll
        for (int bb = 0; bb < 2; ++bb) {
            floatx4 a2 = zero;
#pragma unroll
            for (int kt = 0; kt < 3; ++kt) {
                bf16x8 a = *(const bf16x8*)&H[bb][(s2 * 16 + lrow) * PLB + kt * 32 + lq * 8];
                a2 = __builtin_amdgcn_mfma_f32_16x16x32_bf16(a, F2[kt], a2, 0, 0, 0);
            }
            const int base = bb * NEDGE + eb0;
#pragma unroll
            for (int r_ = 0; r_ < 4; ++r_) {
                int grow = s2 * 16 + lq * 4 + r_;
                if (grow < t)
                    out_edges[(size_t)(base + grow) * 32 + c0o + lrow] = fmaxf(a2[r_] + v2, 0.f);
            }
        }
    }
}

// ---------------- final: node MLP ([pn|nodesb] 192->192->64) ----------------
__global__ __launch_bounds__(192) void k_final(
        const ushort_t* __restrict__ pn, const ushort_t* __restrict__ nodesb,
        const ushort_t* __restrict__ pln1, const float* __restrict__ bln1,
        const ushort_t* __restrict__ pln2, const float* __restrict__ bln2,
        float* __restrict__ out_nodes) {
    __shared__ alignas(16) ushort_t LA[32 * 200];
    __shared__ alignas(16) ushort_t LB[32 * 200];
    const int tid = threadIdx.x;
    const int w = tid >> 6, l = tid & 63, lrow = l & 15, lq = l >> 4;
    floatx4 zero = {0.f, 0.f, 0.f, 0.f};

    int tile = blockIdx.x;
    for (int u = tid; u < 768; u += 192) {        // 32 rows x 24 uint4 chunks
        int row = u / 24, c = u - row * 24;
        int r = tile * 32 + row;
        const uint4* src = (c < 16) ? ((const uint4*)(pn + (size_t)r * 128) + c)
                                    : ((const uint4*)(nodesb + (size_t)r * 64) + (c - 16));
        *(uint4*)&LA[row * 200 + c * 8] = *src;
    }
    bf16x8 f1[6][4]; float v1[4];
#pragma unroll
    for (int kt = 0; kt < 6; ++kt)
#pragma unroll
        for (int nt = 0; nt < 4; ++nt)
            f1[kt][nt] = *(const bf16x8*)(pln1 + (size_t)(w * 64 + nt * 16 + lrow) * 192 + kt * 32 + lq * 8);
#pragma unroll
    for (int nt = 0; nt < 4; ++nt) v1[nt] = bln1[w * 64 + nt * 16 + lrow];
    __syncthreads();

    floatx4 acc[2][4];
#pragma unroll
    for (int s = 0; s < 2; ++s)
#pragma unroll
        for (int nt = 0; nt < 4; ++nt) acc[s][nt] = zero;
#pragma unroll
    for (int s = 0; s < 2; ++s)
#pragma unroll
        for (int kt = 0; kt < 6; ++kt) {
            bf16x8 a = *(const bf16x8*)&LA[(s * 16 + lrow) * 200 + kt * 32 + lq * 8];
#pragma unroll
            for (int nt = 0; nt < 4; ++nt)
                acc[s][nt] = __builtin_amdgcn_mfma_f32_16x16x32_bf16(a, f1[kt][nt], acc[s][nt], 0, 0, 0);
        }
#pragma unroll
    for (int s = 0; s < 2; ++s)
#pragma unroll
        for (int nt = 0; nt < 4; ++nt) {
            int col = w * 64 + nt * 16 + lrow;
#pragma unroll
            for (int r_ = 0; r_ < 4; ++r_)
                LB[(s * 16 + lq * 4 + r_) * 200 + col] = f2b(fmaxf(acc[s][nt][r_] + v1[nt], 0.f));
        }
    bf16x8 f2[6][2]; float v2[2] = {0.f, 0.f};
    if (w < 2) {
#pragma unroll
        for (int kt = 0; kt < 6; ++kt)
#pragma unroll
            for (int nt = 0; nt < 2; ++nt)
                f2[kt][nt] = *(const bf16x8*)(pln2 + (size_t)(w * 32 + nt * 16 + lrow) * 192 + kt * 32 + lq * 8);
#pragma unroll
        for (int nt = 0; nt < 2; ++nt) v2[nt] = bln2[w * 32 + nt * 16 + lrow];
    }
    __syncthreads();
    if (w < 2) {
        floatx4 a2[2][2];
#pragma unroll
        for (int s = 0; s < 2; ++s) { a2[s][0] = zero; a2[s][1] = zero; }
#pragma unroll
        for (int s = 0; s < 2; ++s)
#pragma unroll
            for (int kt = 0; kt < 6; ++kt) {
                bf16x8 a = *(const bf16x8*)&LB[(s * 16 + lrow) * 200 + kt * 32 + lq * 8];
#pragma unroll
                for (int nt = 0; nt < 2; ++nt)
                    a2[s][nt] = __builtin_amdgcn_mfma_f32_16x16x32_bf16(a, f2[kt][nt], a2[s][nt], 0, 0, 0);
            }
#pragma unroll
        for (int s = 0; s < 2; ++s)
#pragma unroll
            for (int nt = 0; nt < 2; ++nt) {
                int col = w * 32 + nt * 16 + lrow;
#pragma unroll
                for (int r_ = 0; r_ < 4; ++r_)
                    out_nodes[(size_t)(tile * 32 + s * 16 + lq * 4 + r_) * 64 + col] =
                        fmaxf(a2[s][nt][r_] + v2[nt], 0.f);
            }
    }
}

extern "C" void kernel_launch(void* const* d_in, const int* in_sizes, int n_in,
                              void* d_out, int out_size, void* d_ws, size_t ws_size,
                              hipStream_t stream) {
    const float* nodes = (const float*)d_in[0];
    const float* edges = (const float*)d_in[1];
    const float* Wan1 = (const float*)d_in[2];  const float* ban1 = (const float*)d_in[3];
    const float* Wan2 = (const float*)d_in[4];  const float* ban2 = (const float*)d_in[5];
    const float* Wln1 = (const float*)d_in[6];  const float* bln1 = (const float*)d_in[7];
    const float* Wln2 = (const float*)d_in[8];  const float* bln2 = (const float*)d_in[9];
    const float* Wae1 = (const float*)d_in[10]; const float* bae1 = (const float*)d_in[11];
    const float* Wae2 = (const float*)d_in[12]; const float* bae2 = (const float*)d_in[13];
    const float* Wle1 = (const float*)d_in[14]; const float* ble1 = (const float*)d_in[15];
    const float* Wle2 = (const float*)d_in[16]; const float* ble2 = (const float*)d_in[17];

    char* ws = (char*)d_ws;
    size_t o = 0;
    auto alloc = [&](size_t bytes) -> void* {
        void* r = ws + o;
        o += (bytes + 255) & ~(size_t)255;
        return r;
    };
    ushort_t* pn     = (ushort_t*)alloc((size_t)2048 * 128 * 2);
    ushort_t* nodesb = (ushort_t*)alloc((size_t)2 * NN * 64 * 2);
    ushort_t* pan1 = (ushort_t*)alloc(160 * 256 * 2);
    ushort_t* pan2 = (ushort_t*)alloc(256 * 128 * 2);
    ushort_t* pae1 = (ushort_t*)alloc(96 * 128 * 2);
    ushort_t* pae2 = (ushort_t*)alloc(128 * 64 * 2);
    ushort_t* ple1 = (ushort_t*)alloc(96 * 96 * 2);
    ushort_t* ple2 = (ushort_t*)alloc(96 * 32 * 2);
    ushort_t* pln1 = (ushort_t*)alloc(192 * 192 * 2);
    ushort_t* pln2 = (ushort_t*)alloc(192 * 64 * 2);

    float* out_nodes = (float*)d_out;
    float* out_edges = (float*)d_out + 2 * NN * 64;

    k_pack<<<280, 256, 0, stream>>>(Wan1, Wan2, Wae1, Wae2, Wle1, Wle2, Wln1, Wln2,
                                    nodes,
                                    pan1, pan2, pae1, pae2, ple1, ple2, pln1, pln2,
                                    nodesb);
    k_main<<<1024, 512, 0, stream>>>(nodesb, edges,
                                     pan1, ban1, pan2, ban2,
                                     pae1, bae1, pae2, bae2,
                                     ple1, ble1, ple2, ble2,
                                     pn, out_edges);
    k_final<<<64, 192, 0, stream>>>(pn, nodesb, pln1, bln1, pln2, bln2, out_nodes);

    (void)in_sizes; (void)n_in; (void)out_size; (void)ws_size;
}